// Round 1
// 1034.786 us; speedup vs baseline: 1.2439x; 1.2439x over previous
//
#include <hip/hip_runtime.h>
#include <hip/hip_bf16.h>
#include <cstdint>
#include <cstddef>
#include <type_traits>

// Problem constants (B,N,D,H fixed by the reference)
#define B_  2
#define N_  2048
#define D_  1024
#define H_  16
#define HD_ 64
#define M_  (B_*N_)   // 4096 rows for the projection GEMMs

typedef __bf16 bf16_t;
typedef bf16_t bf16x8 __attribute__((ext_vector_type(8)));   // 16 B MFMA A/B frag
typedef bf16_t bf16x4 __attribute__((ext_vector_type(4)));   // 8 B LDS store chunk
typedef float  f32x4  __attribute__((ext_vector_type(4)));   // MFMA C/D frag / float4

static_assert(sizeof(bf16x8) == 16, "bf16x8 must be 16B");

__device__ __forceinline__ f32x4 mfma_bf16(bf16x8 a, bf16x8 b, f32x4 c) {
    return __builtin_amdgcn_mfma_f32_16x16x32_bf16(a, b, c, 0, 0, 0);
}

// -------------------------------------------------------------------------
// Y[m,n] = sum_k X[m,k]*W[n,k] + bias[n]   (both operands K-contiguous)
// TX in {float, bf16_t}: staged into LDS as bf16 either way.
// TY in {float, bf16_t}.  W/bias always fp32 (harness inputs).
// Block 256 thr = 4 waves; tile 64x64, BK=64; LDS pitch 72 bf16.
// -------------------------------------------------------------------------
template <typename TX, typename TY>
__global__ __launch_bounds__(256) void proj(const TX* __restrict__ X,
                                            const float* __restrict__ W,
                                            const float* __restrict__ bias,
                                            TY* __restrict__ Y,
                                            int N, int K)
{
    __shared__ __align__(16) bf16_t Xs[64 * 72];
    __shared__ __align__(16) bf16_t Ws[64 * 72];
    const int tid  = threadIdx.x;
    const int wave = tid >> 6;
    const int lane = tid & 63;
    const int l16  = lane & 15;
    const int q    = lane >> 4;
    const int m0   = blockIdx.y * 64;
    const int n0   = blockIdx.x * 64;

    f32x4 acc[4] = {};

    for (int k0 = 0; k0 < K; k0 += 64) {
        __syncthreads();   // protect previous iteration's frag reads
        // --- stage X tile (convert to bf16 if fp32) ---
        if constexpr (std::is_same_v<TX, float>) {
            #pragma unroll
            for (int p = 0; p < 4; p++) {
                int c    = p * 256 + tid;        // 0..1023
                int row  = c >> 4;               // 0..63
                int col4 = (c & 15) * 4;         // 0,4,..,60
                f32x4 v = *(const f32x4*)&X[(size_t)(m0 + row) * K + k0 + col4];
                bf16x4 o;
                #pragma unroll
                for (int e = 0; e < 4; e++) o[e] = (bf16_t)v[e];
                *(bf16x4*)&Xs[row * 72 + col4] = o;
            }
        } else {
            #pragma unroll
            for (int p = 0; p < 2; p++) {
                int c   = p * 256 + tid;
                int row = c >> 3;
                int col = (c & 7) * 8;
                *(bf16x8*)&Xs[row * 72 + col] =
                    *(const bf16x8*)&X[(size_t)(m0 + row) * K + k0 + col];
            }
        }
        // --- stage W tile (fp32 -> bf16) ---
        #pragma unroll
        for (int p = 0; p < 4; p++) {
            int c    = p * 256 + tid;
            int row  = c >> 4;
            int col4 = (c & 15) * 4;
            f32x4 v = *(const f32x4*)&W[(size_t)(n0 + row) * K + k0 + col4];
            bf16x4 o;
            #pragma unroll
            for (int e = 0; e < 4; e++) o[e] = (bf16_t)v[e];
            *(bf16x4*)&Ws[row * 72 + col4] = o;
        }
        __syncthreads();
        #pragma unroll
        for (int ks = 0; ks < 64; ks += 32) {
            bf16x8 a = *(const bf16x8*)&Xs[(wave * 16 + l16) * 72 + ks + q * 8];
            #pragma unroll
            for (int nt = 0; nt < 4; nt++) {
                bf16x8 b = *(const bf16x8*)&Ws[(nt * 16 + l16) * 72 + ks + q * 8];
                acc[nt] = mfma_bf16(a, b, acc[nt]);
            }
        }
    }

    // epilogue: C/D map col=lane&15, row=(lane>>4)*4+reg  [m89/m91 verified]
    #pragma unroll
    for (int nt = 0; nt < 4; nt++) {
        int colg = n0 + nt * 16 + l16;
        float bv = bias[colg];
        #pragma unroll
        for (int reg = 0; reg < 4; reg++) {
            int rowg = m0 + wave * 16 + q * 4 + reg;
            Y[(size_t)rowg * N + colg] = (TY)(acc[nt][reg] + bv);
        }
    }
}

// -------------------------------------------------------------------------
// Pass 1: rinv[row] = 1 / sum_j exp(Q[row]·K[j] * 0.125)
// No P materialization. One block owns 64 rows of one (b,h): no atomics.
// Same MFMA sequence as pass 2 -> logits bitwise identical.
// -------------------------------------------------------------------------
__global__ __launch_bounds__(256) void qk_rowsum(const bf16_t* __restrict__ Q,
                                                 const bf16_t* __restrict__ Km,
                                                 float* __restrict__ rinv)
{
    const int tid  = threadIdx.x;
    const int wave = tid >> 6;
    const int lane = tid & 63;
    const int l16  = lane & 15;
    const int q    = lane >> 4;
    const int bh   = blockIdx.y;      // b*H + h
    const int b    = bh >> 4;         // H_ == 16
    const int h    = bh & 15;
    const int i0   = blockIdx.x * 64;

    const bf16_t* Qp = Q + (size_t)(b * N_ + i0 + wave * 16 + l16) * D_ + h * HD_ + q * 8;
    bf16x8 a0 = *(const bf16x8*)(Qp);
    bf16x8 a1 = *(const bf16x8*)(Qp + 32);

    const float scale = 0.125f;   // 1/sqrt(64)
    float rs[4] = {0.f, 0.f, 0.f, 0.f};

    for (int j0 = 0; j0 < N_; j0 += 128) {
        #pragma unroll
        for (int nt = 0; nt < 8; nt++) {
            const bf16_t* Kp = Km + (size_t)(b * N_ + j0 + nt * 16 + l16) * D_ + h * HD_ + q * 8;
            bf16x8 b0 = *(const bf16x8*)(Kp);
            bf16x8 b1 = *(const bf16x8*)(Kp + 32);
            f32x4 c = {};
            c = mfma_bf16(a0, b0, c);
            c = mfma_bf16(a1, b1, c);
            #pragma unroll
            for (int reg = 0; reg < 4; reg++) rs[reg] += __expf(c[reg] * scale);
        }
    }

    // reduce over the 16 lanes of each quad (same row), write 1/sum
    #pragma unroll
    for (int reg = 0; reg < 4; reg++) {
        float v = rs[reg];
        v += __shfl_xor(v, 1);
        v += __shfl_xor(v, 2);
        v += __shfl_xor(v, 4);
        v += __shfl_xor(v, 8);
        if (l16 == 0) {
            int rowg = i0 + wave * 16 + q * 4 + reg;
            rinv[bh * N_ + rowg] = 1.0f / v;
        }
    }
}

// -------------------------------------------------------------------------
// Pass 2 (fused): recompute S = QK^T, P = exp(S*0.125)*rinv.
//   - write normalized A directly (nontemporal fp32, single HBM pass)
//   - stage P (bf16) + V^T in LDS, accumulate O = P·V in the same block
// Per block: one (b,h), 64 i-rows; j loops 0..N in 64-tiles.
// -------------------------------------------------------------------------
__global__ __launch_bounds__(256) void qk_av(const bf16_t* __restrict__ Q,
                                             const bf16_t* __restrict__ Km,
                                             const bf16_t* __restrict__ V,
                                             const float* __restrict__ rinv,
                                             float* __restrict__ A,
                                             bf16_t* __restrict__ Vh)
{
    __shared__ __align__(16) bf16_t Vt[64 * 72];   // [hd][j] transposed V tile
    __shared__ __align__(16) bf16_t Ps[64 * 72];   // [i][j] P tile (bf16)
    const int tid  = threadIdx.x;
    const int wave = tid >> 6;
    const int lane = tid & 63;
    const int l16  = lane & 15;
    const int q    = lane >> 4;
    const int bh   = blockIdx.y;
    const int b    = bh >> 4;
    const int h    = bh & 15;
    const int i0   = blockIdx.x * 64;

    const bf16_t* Qp = Q + (size_t)(b * N_ + i0 + wave * 16 + l16) * D_ + h * HD_ + q * 8;
    bf16x8 a0 = *(const bf16x8*)(Qp);
    bf16x8 a1 = *(const bf16x8*)(Qp + 32);

    float rv[4];
    #pragma unroll
    for (int reg = 0; reg < 4; reg++)
        rv[reg] = rinv[bh * N_ + i0 + wave * 16 + q * 4 + reg];

    float* Ab = A + ((size_t)bh << 22);   // bh * 2048 * 2048
    const float scale = 0.125f;
    f32x4 acco[4] = {};

    for (int j0 = 0; j0 < N_; j0 += 64) {
        __syncthreads();   // protect previous iteration's LDS reads
        // --- stage V^T tile ---
        #pragma unroll
        for (int p = 0; p < 2; p++) {
            int c  = p * 256 + tid;
            int jr = c >> 3;              // 0..63 (j within tile)
            int hc = (c & 7) * 8;         // 0,8,..,56 (head-dim chunk)
            bf16x8 v = *(const bf16x8*)&V[(size_t)(b * N_ + j0 + jr) * D_ + h * HD_ + hc];
            #pragma unroll
            for (int e = 0; e < 8; e++) Vt[(hc + e) * 72 + jr] = v[e];
        }
        // --- S = QK^T; P = exp*rinv; write A + stage Ps ---
        #pragma unroll
        for (int nt = 0; nt < 4; nt++) {
            const bf16_t* Kp = Km + (size_t)(b * N_ + j0 + nt * 16 + l16) * D_ + h * HD_ + q * 8;
            bf16x8 b0 = *(const bf16x8*)(Kp);
            bf16x8 b1 = *(const bf16x8*)(Kp + 32);
            f32x4 c = {};
            c = mfma_bf16(a0, b0, c);
            c = mfma_bf16(a1, b1, c);
            #pragma unroll
            for (int reg = 0; reg < 4; reg++) {
                float p = __expf(c[reg] * scale) * rv[reg];
                int rowl = wave * 16 + q * 4 + reg;
                int colg = j0 + nt * 16 + l16;
                __builtin_nontemporal_store(p, &Ab[(size_t)(i0 + rowl) * N_ + colg]);
                Ps[rowl * 72 + nt * 16 + l16] = (bf16_t)p;
            }
        }
        __syncthreads();
        // --- O += P·V (A-frags from Ps, B-frags from Vt) ---
        #pragma unroll
        for (int ks = 0; ks < 64; ks += 32) {
            bf16x8 a = *(const bf16x8*)&Ps[(wave * 16 + l16) * 72 + ks + q * 8];
            #pragma unroll
            for (int nt = 0; nt < 4; nt++) {
                bf16x8 bfr = *(const bf16x8*)&Vt[(nt * 16 + l16) * 72 + ks + q * 8];
                acco[nt] = mfma_bf16(a, bfr, acco[nt]);
            }
        }
    }

    #pragma unroll
    for (int nt = 0; nt < 4; nt++) {
        int colg = h * HD_ + nt * 16 + l16;
        #pragma unroll
        for (int reg = 0; reg < 4; reg++) {
            int rowg = i0 + wave * 16 + q * 4 + reg;
            Vh[(size_t)(b * N_ + rowg) * D_ + colg] = (bf16_t)acco[nt][reg];
        }
    }
}

// -------------------------------------------------------------------------
// Launch: Q/K/V proj -> rowsum (no P write) -> fused normalize+A-write+AV
//         -> O proj
// Workspace: Qw/Kw/Vw/Vhw bf16 8MB each | rinv 256KB @ +32MB
// -------------------------------------------------------------------------
extern "C" void kernel_launch(void* const* d_in, const int* in_sizes, int n_in,
                              void* d_out, int out_size, void* d_ws, size_t ws_size,
                              hipStream_t stream)
{
    const float* query = (const float*)d_in[0];
    const float* key   = (const float*)d_in[1];
    const float* value = (const float*)d_in[2];
    const float* Wq = (const float*)d_in[3];
    const float* bq = (const float*)d_in[4];
    const float* Wk = (const float*)d_in[5];
    const float* bk = (const float*)d_in[6];
    const float* Wv = (const float*)d_in[7];
    const float* bv = (const float*)d_in[8];
    const float* Wo = (const float*)d_in[9];
    const float* bo = (const float*)d_in[10];

    float* out  = (float*)d_out;                 // [B,N,D] = 4,194,304 elems
    float* Aout = out + (size_t)B_ * N_ * D_;    // [B,H,N,N] = 134,217,728 elems

    char* ws = (char*)d_ws;
    bf16_t* Qw   = (bf16_t*)(ws);
    bf16_t* Kw   = (bf16_t*)(ws + (size_t)8  * 1024 * 1024);
    bf16_t* Vw   = (bf16_t*)(ws + (size_t)16 * 1024 * 1024);
    bf16_t* Vhw  = (bf16_t*)(ws + (size_t)24 * 1024 * 1024);
    float*  rinv = (float*) (ws + (size_t)32 * 1024 * 1024);

    dim3 blk(256);

    dim3 gproj(D_ / 64, M_ / 64);   // (16, 64)
    proj<float, bf16_t><<<gproj, blk, 0, stream>>>(query, Wq, bq, Qw, D_, D_);
    proj<float, bf16_t><<<gproj, blk, 0, stream>>>(key,   Wk, bk, Kw, D_, D_);
    proj<float, bf16_t><<<gproj, blk, 0, stream>>>(value, Wv, bv, Vw, D_, D_);

    dim3 grs(N_ / 64, B_ * H_);     // (32, 32)
    qk_rowsum<<<grs, blk, 0, stream>>>(Qw, Kw, rinv);

    dim3 gqa(N_ / 64, B_ * H_);     // (32, 32)
    qk_av<<<gqa, blk, 0, stream>>>(Qw, Kw, Vw, rinv, Aout, Vhw);

    proj<bf16_t, float><<<gproj, blk, 0, stream>>>(Vhw, Wo, bo, out, D_, D_);
}

// Round 2
// 882.274 us; speedup vs baseline: 1.4590x; 1.1729x over previous
//
#include <hip/hip_runtime.h>
#include <hip/hip_bf16.h>
#include <cstdint>
#include <cstddef>
#include <type_traits>

// Problem constants (B,N,D,H fixed by the reference)
#define B_  2
#define N_  2048
#define D_  1024
#define H_  16
#define HD_ 64
#define M_  (B_*N_)   // 4096 rows for the projection GEMMs

typedef __bf16 bf16_t;
typedef bf16_t bf16x8 __attribute__((ext_vector_type(8)));   // 16 B MFMA A/B frag
typedef bf16_t bf16x4 __attribute__((ext_vector_type(4)));   // 8 B LDS store chunk
typedef float  f32x4  __attribute__((ext_vector_type(4)));   // MFMA C/D frag / float4

static_assert(sizeof(bf16x8) == 16, "bf16x8 must be 16B");

__device__ __forceinline__ f32x4 mfma_bf16(bf16x8 a, bf16x8 b, f32x4 c) {
    return __builtin_amdgcn_mfma_f32_16x16x32_bf16(a, b, c, 0, 0, 0);
}

// async global->LDS, 16 B per lane. LDS dest is wave-uniform base + lane*16
// (m104: no per-lane LDS scatter -> LDS layout must be linear).
__device__ __forceinline__ void gload_lds16(const bf16_t* g, bf16_t* l) {
    __builtin_amdgcn_global_load_lds(
        (const __attribute__((address_space(1))) uint32_t*)(const void*)g,
        (__attribute__((address_space(3))) uint32_t*)(void*)l,
        16, 0, 0);
}

// -------------------------------------------------------------------------
// One-shot fp32 -> bf16 conversion of q,k,v,Wq,Wk,Wv (8 elems/thread).
// blockIdx.y selects the tensor. Outputs live in the A-output tail region
// (scratch; fully dead before qk_av_fused overwrites A).
// -------------------------------------------------------------------------
__global__ __launch_bounds__(256) void cvt6(
    const float* __restrict__ s0, const float* __restrict__ s1, const float* __restrict__ s2,
    const float* __restrict__ s3, const float* __restrict__ s4, const float* __restrict__ s5,
    bf16_t* __restrict__ d0, bf16_t* __restrict__ d1, bf16_t* __restrict__ d2,
    bf16_t* __restrict__ d3, bf16_t* __restrict__ d4, bf16_t* __restrict__ d5)
{
    const float* src; bf16_t* dst; int n8;
    switch (blockIdx.y) {
        case 0:  src = s0; dst = d0; n8 = (M_*D_)/8; break;
        case 1:  src = s1; dst = d1; n8 = (M_*D_)/8; break;
        case 2:  src = s2; dst = d2; n8 = (M_*D_)/8; break;
        case 3:  src = s3; dst = d3; n8 = (D_*D_)/8; break;
        case 4:  src = s4; dst = d4; n8 = (D_*D_)/8; break;
        default: src = s5; dst = d5; n8 = (D_*D_)/8; break;
    }
    int c = blockIdx.x * 256 + threadIdx.x;
    if (c >= n8) return;
    const f32x4* sp = (const f32x4*)(src + (size_t)c * 8);
    f32x4 v0 = sp[0], v1 = sp[1];
    bf16x8 o;
    #pragma unroll
    for (int e = 0; e < 4; e++) { o[e] = (bf16_t)v0[e]; o[e + 4] = (bf16_t)v1[e]; }
    *(bf16x8*)(dst + (size_t)c * 8) = o;
}

// -------------------------------------------------------------------------
// Y[m,n] = sum_k X[m,k]*W[n,k] + bias[n].  X always bf16 (pre-converted),
// staged via global_load_lds width-16 into a LINEAR [64][64] tile.
// WBF16=true: W likewise. WBF16=false (O-proj): W fp32, VALU-staged, pitch 72.
// Block 256 thr = 4 waves; tile 64x64, BK=64.
// -------------------------------------------------------------------------
template <bool WBF16, typename TY>
__global__ __launch_bounds__(256) void projb(const bf16_t* __restrict__ X,
                                             const void* __restrict__ Wp,
                                             const float* __restrict__ bias,
                                             TY* __restrict__ Y,
                                             int N, int K)
{
    __shared__ __align__(16) bf16_t Xs[64 * 64];   // linear: global_load_lds dest
    __shared__ __align__(16) bf16_t Ws[64 * 72];   // pitch 64 (bf16) or 72 (fp32 path)
    constexpr int WP = WBF16 ? 64 : 72;
    const int tid  = threadIdx.x;
    const int wave = tid >> 6;
    const int lane = tid & 63;
    const int l16  = lane & 15;
    const int q    = lane >> 4;
    const int m0   = blockIdx.y * 64;
    const int n0   = blockIdx.x * 64;

    f32x4 acc[4] = {};

    for (int k0 = 0; k0 < K; k0 += 64) {
        __syncthreads();   // protect previous iteration's frag reads
        // --- X tile: 2 async 1KB wave-loads, granule g -> (row=g>>3, col=(g&7)*8)
        #pragma unroll
        for (int i = 0; i < 2; i++) {
            int g = wave * 128 + i * 64 + lane;
            gload_lds16(&X[(size_t)(m0 + (g >> 3)) * K + k0 + (lane & 7) * 8],
                        &Xs[(wave * 128 + i * 64) * 8]);
        }
        if constexpr (WBF16) {
            const bf16_t* Wb = (const bf16_t*)Wp;
            #pragma unroll
            for (int i = 0; i < 2; i++) {
                int g = wave * 128 + i * 64 + lane;
                gload_lds16(&Wb[(size_t)(n0 + (g >> 3)) * K + k0 + (lane & 7) * 8],
                            &Ws[(wave * 128 + i * 64) * 8]);
            }
        } else {
            const float* Wf = (const float*)Wp;
            #pragma unroll
            for (int p = 0; p < 4; p++) {
                int c    = p * 256 + tid;
                int row  = c >> 4;
                int col4 = (c & 15) * 4;
                f32x4 v = *(const f32x4*)&Wf[(size_t)(n0 + row) * K + k0 + col4];
                bf16x4 o;
                #pragma unroll
                for (int e = 0; e < 4; e++) o[e] = (bf16_t)v[e];
                *(bf16x4*)&Ws[row * 72 + col4] = o;
            }
        }
        __syncthreads();   // drains vmcnt(0): global_load_lds data visible
        #pragma unroll
        for (int ks = 0; ks < 64; ks += 32) {
            bf16x8 a = *(const bf16x8*)&Xs[(wave * 16 + l16) * 64 + ks + q * 8];
            #pragma unroll
            for (int nt = 0; nt < 4; nt++) {
                bf16x8 b = *(const bf16x8*)&Ws[(nt * 16 + l16) * WP + ks + q * 8];
                acc[nt] = mfma_bf16(a, b, acc[nt]);
            }
        }
    }

    // epilogue: C/D map col=lane&15, row=(lane>>4)*4+reg  [m89/m91 verified]
    #pragma unroll
    for (int nt = 0; nt < 4; nt++) {
        int colg = n0 + nt * 16 + l16;
        float bv = bias[colg];
        #pragma unroll
        for (int reg = 0; reg < 4; reg++) {
            int rowg = m0 + wave * 16 + q * 4 + reg;
            Y[(size_t)rowg * N + colg] = (TY)(acc[nt][reg] + bv);
        }
    }
}

// -------------------------------------------------------------------------
// Fused attention core. Per block: one (b,h), 64 i-rows.
// Phase 1 (pure-register, no LDS/barriers): rowsums of exp(QK^T*scale),
//   butterfly-reduced in-wave -> rv = 1/rowsum. No global round-trip.
// Phase 2: recompute S (bitwise-identical MFMA), P = exp*rv staged fp32 in
//   LDS, then (a) coalesced f32x4 nontemporal A write (256B row segments),
//   (b) PV MFMA with A-frags read+cvt from the same fp32 tile.
// -------------------------------------------------------------------------
__global__ __launch_bounds__(256) void qk_av_fused(const bf16_t* __restrict__ Q,
                                                   const bf16_t* __restrict__ Km,
                                                   const bf16_t* __restrict__ V,
                                                   float* __restrict__ A,
                                                   bf16_t* __restrict__ Vh)
{
    __shared__ __align__(16) bf16_t Vt[64 * 72];   // [hd][j] transposed V tile
    __shared__ __align__(16) float  Pf[64 * 68];   // [i][j] P tile, fp32, pitch 68
    const int tid  = threadIdx.x;
    const int wave = tid >> 6;
    const int lane = tid & 63;
    const int l16  = lane & 15;
    const int q    = lane >> 4;
    const int bh   = blockIdx.y;
    const int b    = bh >> 4;
    const int h    = bh & 15;
    const int i0   = blockIdx.x * 64;

    const bf16_t* Qp = Q + (size_t)(b * N_ + i0 + wave * 16 + l16) * D_ + h * HD_ + q * 8;
    bf16x8 a0 = *(const bf16x8*)(Qp);
    bf16x8 a1 = *(const bf16x8*)(Qp + 32);

    const float scale = 0.125f;   // 1/sqrt(64); logits bounded, no max needed

    // ---- phase 1: rowsums ----
    float rs[4] = {0.f, 0.f, 0.f, 0.f};
    for (int j0 = 0; j0 < N_; j0 += 128) {
        #pragma unroll
        for (int nt = 0; nt < 8; nt++) {
            const bf16_t* Kp = Km + (size_t)(b * N_ + j0 + nt * 16 + l16) * D_ + h * HD_ + q * 8;
            bf16x8 b0 = *(const bf16x8*)(Kp);
            bf16x8 b1 = *(const bf16x8*)(Kp + 32);
            f32x4 c = {};
            c = mfma_bf16(a0, b0, c);
            c = mfma_bf16(a1, b1, c);
            #pragma unroll
            for (int reg = 0; reg < 4; reg++) rs[reg] += __expf(c[reg] * scale);
        }
    }
    float rv[4];
    #pragma unroll
    for (int reg = 0; reg < 4; reg++) {
        float v = rs[reg];          // 16 lanes of each quad share a row:
        v += __shfl_xor(v, 1);      // full butterfly -> every lane has the sum
        v += __shfl_xor(v, 2);
        v += __shfl_xor(v, 4);
        v += __shfl_xor(v, 8);
        rv[reg] = 1.0f / v;
    }

    // ---- phase 2: normalized A write + PV ----
    float* Ab = A + ((size_t)bh << 22);   // bh * 2048 * 2048
    f32x4 acco[4] = {};

    for (int j0 = 0; j0 < N_; j0 += 64) {
        __syncthreads();   // protect previous iteration's Pf/Vt reads
        // stage V^T tile
        #pragma unroll
        for (int p = 0; p < 2; p++) {
            int c  = p * 256 + tid;
            int jr = c >> 3;              // 0..63 (j within tile)
            int hc = (c & 7) * 8;         // 0,8,..,56 (head-dim chunk)
            bf16x8 v = *(const bf16x8*)&V[(size_t)(b * N_ + j0 + jr) * D_ + h * HD_ + hc];
            #pragma unroll
            for (int e = 0; e < 8; e++) Vt[(hc + e) * 72 + jr] = v[e];
        }
        // S = QK^T (same frag math as phase 1); P = exp*rv -> Pf (fp32)
        #pragma unroll
        for (int nt = 0; nt < 4; nt++) {
            const bf16_t* Kp = Km + (size_t)(b * N_ + j0 + nt * 16 + l16) * D_ + h * HD_ + q * 8;
            bf16x8 b0 = *(const bf16x8*)(Kp);
            bf16x8 b1 = *(const bf16x8*)(Kp + 32);
            f32x4 c = {};
            c = mfma_bf16(a0, b0, c);
            c = mfma_bf16(a1, b1, c);
            #pragma unroll
            for (int reg = 0; reg < 4; reg++) {
                float p = __expf(c[reg] * scale) * rv[reg];
                Pf[(wave * 16 + q * 4 + reg) * 68 + nt * 16 + l16] = p;
            }
        }
        __syncthreads();
        // A write: 4 rows x 256 B contiguous per wave, nontemporal f32x4
        #pragma unroll
        for (int k = 0; k < 4; k++) {
            int row  = k * 16 + (tid >> 4);
            int col4 = (tid & 15) * 4;
            f32x4 v = *(const f32x4*)&Pf[row * 68 + col4];
            __builtin_nontemporal_store(v, (f32x4*)&Ab[(size_t)(i0 + row) * N_ + j0 + col4]);
        }
        // PV: A-frags from Pf (fp32 -> bf16), B-frags from Vt
        #pragma unroll
        for (int ks = 0; ks < 64; ks += 32) {
            const float* pp = &Pf[(wave * 16 + l16) * 68 + ks + q * 8];
            f32x4 p0 = *(const f32x4*)(pp);
            f32x4 p1 = *(const f32x4*)(pp + 4);
            bf16x8 a;
            #pragma unroll
            for (int e = 0; e < 4; e++) { a[e] = (bf16_t)p0[e]; a[e + 4] = (bf16_t)p1[e]; }
            #pragma unroll
            for (int nt = 0; nt < 4; nt++) {
                bf16x8 bfr = *(const bf16x8*)&Vt[(nt * 16 + l16) * 72 + ks + q * 8];
                acco[nt] = mfma_bf16(a, bfr, acco[nt]);
            }
        }
    }

    #pragma unroll
    for (int nt = 0; nt < 4; nt++) {
        int colg = h * HD_ + nt * 16 + l16;
        #pragma unroll
        for (int reg = 0; reg < 4; reg++) {
            int rowg = i0 + wave * 16 + q * 4 + reg;
            Vh[(size_t)(b * N_ + rowg) * D_ + colg] = (bf16_t)acco[nt][reg];
        }
    }
}

// -------------------------------------------------------------------------
// Launch: cvt(q,k,v,Wq,Wk,Wv -> bf16 in A-tail scratch) -> Q/K/V proj
//         -> fused rowsum+normalize+A-write+PV -> O proj (fp32 Wo path)
// Workspace: Qw/Kw/Vw/Vhw bf16 8MB each = 32MB total.
// bf16 scratch lives in the last 32MB of Aout (dead before A is written).
// -------------------------------------------------------------------------
extern "C" void kernel_launch(void* const* d_in, const int* in_sizes, int n_in,
                              void* d_out, int out_size, void* d_ws, size_t ws_size,
                              hipStream_t stream)
{
    const float* query = (const float*)d_in[0];
    const float* key   = (const float*)d_in[1];
    const float* value = (const float*)d_in[2];
    const float* Wq = (const float*)d_in[3];
    const float* bq = (const float*)d_in[4];
    const float* Wk = (const float*)d_in[5];
    const float* bk = (const float*)d_in[6];
    const float* Wv = (const float*)d_in[7];
    const float* bv = (const float*)d_in[8];
    const float* Wo = (const float*)d_in[9];
    const float* bo = (const float*)d_in[10];

    float* out  = (float*)d_out;                 // [B,N,D] = 4,194,304 elems
    float* Aout = out + (size_t)B_ * N_ * D_;    // [B,H,N,N] = 134,217,728 elems

    // scratch in the tail of Aout (536,870,912 B): last 32 MB
    char* scr = (char*)Aout + ((size_t)536870912 - (size_t)32 * 1024 * 1024);
    bf16_t* qb  = (bf16_t*)(scr);
    bf16_t* kb  = (bf16_t*)(scr + (size_t)8  * 1024 * 1024);
    bf16_t* vb  = (bf16_t*)(scr + (size_t)16 * 1024 * 1024);
    bf16_t* Wqb = (bf16_t*)(scr + (size_t)24 * 1024 * 1024);
    bf16_t* Wkb = (bf16_t*)(scr + (size_t)26 * 1024 * 1024);
    bf16_t* Wvb = (bf16_t*)(scr + (size_t)28 * 1024 * 1024);

    char* ws = (char*)d_ws;
    bf16_t* Qw   = (bf16_t*)(ws);
    bf16_t* Kw   = (bf16_t*)(ws + (size_t)8  * 1024 * 1024);
    bf16_t* Vw   = (bf16_t*)(ws + (size_t)16 * 1024 * 1024);
    bf16_t* Vhw  = (bf16_t*)(ws + (size_t)24 * 1024 * 1024);

    dim3 blk(256);

    cvt6<<<dim3(2048, 6), blk, 0, stream>>>(query, key, value, Wq, Wk, Wv,
                                            qb, kb, vb, Wqb, Wkb, Wvb);

    dim3 gproj(D_ / 64, M_ / 64);   // (16, 64)
    projb<true,  bf16_t><<<gproj, blk, 0, stream>>>(qb, Wqb, bq, Qw, D_, D_);
    projb<true,  bf16_t><<<gproj, blk, 0, stream>>>(kb, Wkb, bk, Kw, D_, D_);
    projb<true,  bf16_t><<<gproj, blk, 0, stream>>>(vb, Wvb, bv, Vw, D_, D_);

    dim3 gqa(N_ / 64, B_ * H_);     // (32, 32)
    qk_av_fused<<<gqa, blk, 0, stream>>>(Qw, Kw, Vw, Aout, Vhw);

    projb<false, float><<<gproj, blk, 0, stream>>>(Vhw, Wo, bo, out, D_, D_);
}